// Round 2
// baseline (1197.078 us; speedup 1.0000x reference)
//
#include <hip/hip_runtime.h>

#define TPB 256

// ---------------- degree histogram ----------------
__global__ void deg_kernel(const int* __restrict__ dst,
                           float* __restrict__ deg, int E) {
    int t = blockIdx.x * blockDim.x + threadIdx.x;
    if (t < E) atomicAdd(&deg[dst[t]], 1.0f);
}

__global__ void inv_kernel(float* __restrict__ deg, int N) {
    int t = blockIdx.x * blockDim.x + threadIdx.x;
    if (t < N) deg[t] = 1.0f / fmaxf(deg[t], 1.0f);
}

// ---------------- dual GEMM:  Y = A@Wl,  C = A@Wr + b ----------------
// A: [N][K] row-major. Optionally relu(A) on load (for layer 2).
// 256 threads, NPB nodes per block, each thread computes a 2-node x 4-output
// micro-tile. W (K x 2F) and the A-tile live in LDS.
template <int K, int F, bool RELU>
__global__ __launch_bounds__(256) void gemm_dual(
    const float* __restrict__ A,
    const float* __restrict__ Wl, const float* __restrict__ Wr,
    const float* __restrict__ b,
    float* __restrict__ Y, float* __restrict__ C, int N)
{
    constexpr int F2   = 2 * F;        // combined outputs
    constexpr int JG   = F2 / 4;       // 4-wide output groups
    constexpr int NPB  = 2 * 256 / JG; // nodes per block (micro = 2 nodes)
    constexpr int APAD = K + 4;        // keeps 16B alignment, breaks bank stride

    __shared__ float Wsm[K * F2];
    __shared__ float Asm[NPB * APAD];

    const int tid = threadIdx.x;

    // stage W (k-major, [K][F2], Wl in cols 0..F-1, Wr in cols F..2F-1)
    for (int i = tid; i < K * F2; i += 256) {
        int k = i / F2, j = i % F2;
        Wsm[i] = (j < F) ? Wl[k * F + j] : Wr[k * F + (j - F)];
    }

    // stage A tile (coalesced float4 global reads)
    const int node0 = blockIdx.x * NPB;
    constexpr int NF4 = NPB * K / 4;
    for (int f4 = tid; f4 < NF4; f4 += 256) {
        int n  = f4 / (K / 4);
        int kq = f4 % (K / 4);
        int gn = node0 + n;
        float4 v = make_float4(0.f, 0.f, 0.f, 0.f);
        if (gn < N) v = *(const float4*)&A[(size_t)gn * K + kq * 4];
        if (RELU) {
            v.x = fmaxf(v.x, 0.f); v.y = fmaxf(v.y, 0.f);
            v.z = fmaxf(v.z, 0.f); v.w = fmaxf(v.w, 0.f);
        }
        *(float4*)&Asm[n * APAD + kq * 4] = v;
    }
    __syncthreads();

    const int j0 = (tid % JG) * 4;
    const int n0 = (tid / JG) * 2;

    float acc[2][4] = {};
    #pragma unroll 4
    for (int k = 0; k < K; k += 4) {
        float4 a0 = *(const float4*)&Asm[n0 * APAD + k];
        float4 a1 = *(const float4*)&Asm[(n0 + 1) * APAD + k];
        #pragma unroll
        for (int kk = 0; kk < 4; ++kk) {
            float4 wv = *(const float4*)&Wsm[(k + kk) * F2 + j0];
            float av0 = ((const float*)&a0)[kk];
            float av1 = ((const float*)&a1)[kk];
            acc[0][0] += av0 * wv.x; acc[0][1] += av0 * wv.y;
            acc[0][2] += av0 * wv.z; acc[0][3] += av0 * wv.w;
            acc[1][0] += av1 * wv.x; acc[1][1] += av1 * wv.y;
            acc[1][2] += av1 * wv.z; acc[1][3] += av1 * wv.w;
        }
    }

    const bool isY = (j0 < F);
    const int  jj  = isY ? j0 : (j0 - F);
    float4 bias = make_float4(0.f, 0.f, 0.f, 0.f);
    if (!isY) bias = *(const float4*)&b[jj];
    float* dstp = isY ? Y : C;
    #pragma unroll
    for (int m = 0; m < 2; ++m) {
        int gn = node0 + n0 + m;
        if (gn < N) {
            float4 r;
            r.x = acc[m][0] + bias.x;
            r.y = acc[m][1] + bias.y;
            r.z = acc[m][2] + bias.z;
            r.w = acc[m][3] + bias.w;
            *(float4*)&dstp[(size_t)gn * F + jj] = r;
        }
    }
}

// ---------------- edge scatter:  C[dst] += Y[src] * inv_deg[dst] ----------------
template <int F>
__global__ void scatter_kernel(const int* __restrict__ src,
                               const int* __restrict__ dst,
                               const float* __restrict__ invdeg,
                               const float* __restrict__ Y,
                               float* __restrict__ C, long total)
{
    constexpr int VPE = F / 4;  // float4 groups per edge
    long t = (long)blockIdx.x * blockDim.x + threadIdx.x;
    if (t >= total) return;
    int e = (int)(t / VPE);
    int q = (int)(t % VPE);
    int s = src[e];
    int d = dst[e];
    float w = invdeg[d];
    float4 v = *(const float4*)&Y[(size_t)s * F + q * 4];
    float* o = &C[(size_t)d * F + q * 4];
    atomicAdd(o + 0, v.x * w);
    atomicAdd(o + 1, v.y * w);
    atomicAdd(o + 2, v.z * w);
    atomicAdd(o + 3, v.w * w);
}

// ---------------- final: out = relu(c2) @ Wfc + bfc ----------------
__global__ void final_kernel(const float* __restrict__ c2,
                             const float* __restrict__ Wfc,
                             const float* __restrict__ bfc,
                             float* __restrict__ out, int N)
{
    int t = blockIdx.x * blockDim.x + threadIdx.x;
    if (t >= N) return;
    float o0 = bfc[0], o1 = bfc[1];
    #pragma unroll
    for (int c = 0; c < 16; ++c) {
        float h = fmaxf(c2[(size_t)t * 16 + c], 0.f);
        o0 += h * Wfc[c * 2 + 0];
        o1 += h * Wfc[c * 2 + 1];
    }
    ((float2*)out)[t] = make_float2(o0, o1);
}

extern "C" void kernel_launch(void* const* d_in, const int* in_sizes, int n_in,
                              void* d_out, int out_size, void* d_ws, size_t ws_size,
                              hipStream_t stream)
{
    const float* x   = (const float*)d_in[0];
    const int*   ei  = (const int*)d_in[1];   // int32! (JAX default, harness rule)
    const float* W1l = (const float*)d_in[2];
    const float* b1  = (const float*)d_in[3];
    const float* W1r = (const float*)d_in[4];
    const float* W2l = (const float*)d_in[5];
    const float* b2  = (const float*)d_in[6];
    const float* W2r = (const float*)d_in[7];
    const float* Wfc = (const float*)d_in[8];
    const float* bfc = (const float*)d_in[9];
    float* out = (float*)d_out;

    const int N = in_sizes[0] / 128;
    const int E = in_sizes[1] / 2;
    const int* src = ei;
    const int* dst = ei + E;

    float* ws  = (float*)d_ws;
    float* deg = ws;                       // N
    float* y1  = deg + N;                  // N*32
    float* c1  = y1 + (size_t)N * 32;      // N*32
    float* y2  = c1 + (size_t)N * 32;      // N*16
    float* c2  = y2 + (size_t)N * 16;      // N*16

    hipMemsetAsync(deg, 0, (size_t)N * sizeof(float), stream);
    deg_kernel<<<(E + TPB - 1) / TPB, TPB, 0, stream>>>(dst, deg, E);
    inv_kernel<<<(N + TPB - 1) / TPB, TPB, 0, stream>>>(deg, N);

    // layer 1: y1 = x@W1l, c1 = x@W1r + b1
    gemm_dual<128, 32, false><<<(N + 31) / 32, TPB, 0, stream>>>(
        x, W1l, W1r, b1, y1, c1, N);
    {
        long total = (long)E * 8;
        scatter_kernel<32><<<(int)((total + TPB - 1) / TPB), TPB, 0, stream>>>(
            src, dst, deg, y1, c1, total);
    }

    // layer 2: y2 = relu(c1)@W2l, c2 = relu(c1)@W2r + b2
    gemm_dual<32, 16, true><<<(N + 63) / 64, TPB, 0, stream>>>(
        c1, W2l, W2r, b2, y2, c2, N);
    {
        long total = (long)E * 4;
        scatter_kernel<16><<<(int)((total + TPB - 1) / TPB), TPB, 0, stream>>>(
            src, dst, deg, y2, c2, total);
    }

    final_kernel<<<(N + TPB - 1) / TPB, TPB, 0, stream>>>(c2, Wfc, bfc, out, N);
}

// Round 3
// 627.272 us; speedup vs baseline: 1.9084x; 1.9084x over previous
//
#include <hip/hip_runtime.h>

#define TPB 256

// ---------------- degree histogram (int atomics on 400KB counter array) ----
__global__ void hist_kernel(const int* __restrict__ dst,
                            int* __restrict__ cnt, int E) {
    int t = blockIdx.x * blockDim.x + threadIdx.x;
    if (t < E) atomicAdd(&cnt[dst[t]], 1);
}

// ---------------- single-block exclusive scan of cnt[N] -------------------
// 1024 threads, each owns a contiguous chunk; Hillis-Steele over chunk sums.
// Writes row_start (exclusive prefix) AND cursor (copy of row_start; the
// fill kernel's atomic appends advance cursor to the row END).
__global__ __launch_bounds__(1024) void scan_kernel(
    const int* __restrict__ cnt,
    int* __restrict__ row_start, int* __restrict__ cursor, int N)
{
    __shared__ int sums[1024];
    const int t = threadIdx.x;
    const int chunk = (N + 1023) >> 10;
    const int lo = t * chunk;
    const int hi = min(lo + chunk, N);
    int s = 0;
    for (int i = lo; i < hi; ++i) s += cnt[i];
    sums[t] = s;
    __syncthreads();
    for (int off = 1; off < 1024; off <<= 1) {
        int v = (t >= off) ? sums[t - off] : 0;
        __syncthreads();
        sums[t] += v;
        __syncthreads();
    }
    int base = (t == 0) ? 0 : sums[t - 1];
    for (int i = lo; i < hi; ++i) {
        row_start[i] = base;
        cursor[i]    = base;
        base += cnt[i];
    }
}

// ---------------- CSR fill: csr_src[cursor[d]++] = s -----------------------
__global__ void fill_kernel(const int* __restrict__ src,
                            const int* __restrict__ dst,
                            int* __restrict__ cursor,
                            int* __restrict__ csr_src, int E)
{
    int t = blockIdx.x * blockDim.x + threadIdx.x;
    if (t < E) {
        int pos = atomicAdd(&cursor[dst[t]], 1);
        csr_src[pos] = src[t];
    }
}

// ---------------- dual GEMM:  Y = A@Wl,  C = A@Wr + b ----------------
template <int K, int F, bool RELU>
__global__ __launch_bounds__(256) void gemm_dual(
    const float* __restrict__ A,
    const float* __restrict__ Wl, const float* __restrict__ Wr,
    const float* __restrict__ b,
    float* __restrict__ Y, float* __restrict__ C, int N)
{
    constexpr int F2   = 2 * F;
    constexpr int JG   = F2 / 4;
    constexpr int NPB  = 2 * 256 / JG;
    constexpr int APAD = K + 4;

    __shared__ float Wsm[K * F2];
    __shared__ float Asm[NPB * APAD];

    const int tid = threadIdx.x;

    for (int i = tid; i < K * F2; i += 256) {
        int k = i / F2, j = i % F2;
        Wsm[i] = (j < F) ? Wl[k * F + j] : Wr[k * F + (j - F)];
    }

    const int node0 = blockIdx.x * NPB;
    constexpr int NF4 = NPB * K / 4;
    for (int f4 = tid; f4 < NF4; f4 += 256) {
        int n  = f4 / (K / 4);
        int kq = f4 % (K / 4);
        int gn = node0 + n;
        float4 v = make_float4(0.f, 0.f, 0.f, 0.f);
        if (gn < N) v = *(const float4*)&A[(size_t)gn * K + kq * 4];
        if (RELU) {
            v.x = fmaxf(v.x, 0.f); v.y = fmaxf(v.y, 0.f);
            v.z = fmaxf(v.z, 0.f); v.w = fmaxf(v.w, 0.f);
        }
        *(float4*)&Asm[n * APAD + kq * 4] = v;
    }
    __syncthreads();

    const int j0 = (tid % JG) * 4;
    const int n0 = (tid / JG) * 2;

    float acc[2][4] = {};
    #pragma unroll 4
    for (int k = 0; k < K; k += 4) {
        float4 a0 = *(const float4*)&Asm[n0 * APAD + k];
        float4 a1 = *(const float4*)&Asm[(n0 + 1) * APAD + k];
        #pragma unroll
        for (int kk = 0; kk < 4; ++kk) {
            float4 wv = *(const float4*)&Wsm[(k + kk) * F2 + j0];
            float av0 = ((const float*)&a0)[kk];
            float av1 = ((const float*)&a1)[kk];
            acc[0][0] += av0 * wv.x; acc[0][1] += av0 * wv.y;
            acc[0][2] += av0 * wv.z; acc[0][3] += av0 * wv.w;
            acc[1][0] += av1 * wv.x; acc[1][1] += av1 * wv.y;
            acc[1][2] += av1 * wv.z; acc[1][3] += av1 * wv.w;
        }
    }

    const bool isY = (j0 < F);
    const int  jj  = isY ? j0 : (j0 - F);
    float4 bias = make_float4(0.f, 0.f, 0.f, 0.f);
    if (!isY) bias = *(const float4*)&b[jj];
    float* dstp = isY ? Y : C;
    #pragma unroll
    for (int m = 0; m < 2; ++m) {
        int gn = node0 + n0 + m;
        if (gn < N) {
            float4 r;
            r.x = acc[m][0] + bias.x;
            r.y = acc[m][1] + bias.y;
            r.z = acc[m][2] + bias.z;
            r.w = acc[m][3] + bias.w;
            *(float4*)&dstp[(size_t)gn * F + jj] = r;
        }
    }
}

// ---------------- CSR gather:  C[i] += (1/deg_i) * sum_{j in in(i)} Y[j] ---
// TPN = F/4 threads per node, each owning one float4 lane-group.
template <int F>
__global__ void gather_kernel(const int* __restrict__ row_start,
                              const int* __restrict__ row_end,  // == cursor after fill
                              const int* __restrict__ csr_src,
                              const float* __restrict__ Y,
                              float* __restrict__ C, int N)
{
    constexpr int TPN = F / 4;
    int gid  = blockIdx.x * blockDim.x + threadIdx.x;
    int node = gid / TPN;
    int q    = gid % TPN;
    if (node >= N) return;

    int start = row_start[node];
    int end   = row_end[node];
    float w   = 1.0f / fmaxf((float)(end - start), 1.0f);

    float4 acc = make_float4(0.f, 0.f, 0.f, 0.f);
    for (int j = start; j < end; ++j) {
        int s = csr_src[j];
        float4 v = *(const float4*)&Y[(size_t)s * F + q * 4];
        acc.x += v.x; acc.y += v.y; acc.z += v.z; acc.w += v.w;
    }

    float* o = &C[(size_t)node * F + q * 4];
    float4 c = *(const float4*)o;
    c.x += acc.x * w; c.y += acc.y * w;
    c.z += acc.z * w; c.w += acc.w * w;
    *(float4*)o = c;
}

// ---------------- final: out = relu(c2) @ Wfc + bfc ----------------
__global__ void final_kernel(const float* __restrict__ c2,
                             const float* __restrict__ Wfc,
                             const float* __restrict__ bfc,
                             float* __restrict__ out, int N)
{
    int t = blockIdx.x * blockDim.x + threadIdx.x;
    if (t >= N) return;
    float o0 = bfc[0], o1 = bfc[1];
    #pragma unroll
    for (int c = 0; c < 16; ++c) {
        float h = fmaxf(c2[(size_t)t * 16 + c], 0.f);
        o0 += h * Wfc[c * 2 + 0];
        o1 += h * Wfc[c * 2 + 1];
    }
    ((float2*)out)[t] = make_float2(o0, o1);
}

extern "C" void kernel_launch(void* const* d_in, const int* in_sizes, int n_in,
                              void* d_out, int out_size, void* d_ws, size_t ws_size,
                              hipStream_t stream)
{
    const float* x   = (const float*)d_in[0];
    const int*   ei  = (const int*)d_in[1];   // int32 (JAX default)
    const float* W1l = (const float*)d_in[2];
    const float* b1  = (const float*)d_in[3];
    const float* W1r = (const float*)d_in[4];
    const float* W2l = (const float*)d_in[5];
    const float* b2  = (const float*)d_in[6];
    const float* W2r = (const float*)d_in[7];
    const float* Wfc = (const float*)d_in[8];
    const float* bfc = (const float*)d_in[9];
    float* out = (float*)d_out;

    const int N = in_sizes[0] / 128;
    const int E = in_sizes[1] / 2;
    const int* src = ei;
    const int* dst = ei + E;

    // workspace layout (≈33 MB): ints first, then float buffers.
    int*   cnt       = (int*)d_ws;                 // N
    int*   row_start = cnt + N;                    // N
    int*   cursor    = row_start + N;              // N (post-fill: row END)
    int*   csr_src   = cursor + N;                 // E
    float* y1        = (float*)(csr_src + E);      // N*32
    float* c1        = y1 + (size_t)N * 32;        // N*32
    float* y2        = y1;                         // N*16 (overlays dead y1)
    float* c2        = y1 + (size_t)N * 16;        // N*16

    // ---- build CSR ----
    hipMemsetAsync(cnt, 0, (size_t)N * sizeof(int), stream);
    hist_kernel<<<(E + TPB - 1) / TPB, TPB, 0, stream>>>(dst, cnt, E);
    scan_kernel<<<1, 1024, 0, stream>>>(cnt, row_start, cursor, N);
    fill_kernel<<<(E + TPB - 1) / TPB, TPB, 0, stream>>>(src, dst, cursor, csr_src, E);

    // ---- layer 1: y1 = x@W1l, c1 = x@W1r + b1; c1 += mean(y1[in(i)]) ----
    gemm_dual<128, 32, false><<<(N + 31) / 32, TPB, 0, stream>>>(
        x, W1l, W1r, b1, y1, c1, N);
    gather_kernel<32><<<(N * 8 + TPB - 1) / TPB, TPB, 0, stream>>>(
        row_start, cursor, csr_src, y1, c1, N);

    // ---- layer 2: y2 = relu(c1)@W2l, c2 = relu(c1)@W2r + b2; c2 += mean ----
    gemm_dual<32, 16, true><<<(N + 63) / 64, TPB, 0, stream>>>(
        c1, W2l, W2r, b2, y2, c2, N);
    gather_kernel<16><<<(N * 4 + TPB - 1) / TPB, TPB, 0, stream>>>(
        row_start, cursor, csr_src, y2, c2, N);

    // ---- final ----
    final_kernel<<<(N + TPB - 1) / TPB, TPB, 0, stream>>>(c2, Wfc, bfc, out, N);
}

// Round 4
// 399.715 us; speedup vs baseline: 2.9948x; 1.5693x over previous
//
#include <hip/hip_runtime.h>

#define TPB 256

// ---------------- degree histogram (int atomics on 400KB counter array) ----
__global__ void hist_kernel(const int* __restrict__ dst,
                            int* __restrict__ cnt, int E) {
    int t = blockIdx.x * blockDim.x + threadIdx.x;
    if (t < E) atomicAdd(&cnt[dst[t]], 1);
}

// ---------------- hierarchical scan: stage 1 — per-block sums -------------
// Each block owns 1024 counters (256 thr x 4). Writes block_sums[b].
__global__ __launch_bounds__(256) void scan_partial(
    const int* __restrict__ cnt, int* __restrict__ block_sums, int N)
{
    __shared__ int red[256];
    const int t = threadIdx.x;
    const int base = blockIdx.x * 1024 + t * 4;
    int s = 0;
    if (base + 3 < N) {
        int4 v = *(const int4*)&cnt[base];
        s = v.x + v.y + v.z + v.w;
    } else {
        for (int i = 0; i < 4; ++i) if (base + i < N) s += cnt[base + i];
    }
    red[t] = s;
    __syncthreads();
    for (int off = 128; off > 0; off >>= 1) {
        if (t < off) red[t] += red[t + off];
        __syncthreads();
    }
    if (t == 0) block_sums[blockIdx.x] = red[0];
}

// ---------------- stage 2 — exclusive scan of block sums (NB <= 256) ------
__global__ __launch_bounds__(256) void scan_blocksums(
    int* __restrict__ block_sums, int NB)
{
    __shared__ int sums[256];
    const int t = threadIdx.x;
    int v = (t < NB) ? block_sums[t] : 0;
    sums[t] = v;
    __syncthreads();
    for (int off = 1; off < 256; off <<= 1) {
        int u = (t >= off) ? sums[t - off] : 0;
        __syncthreads();
        sums[t] += u;
        __syncthreads();
    }
    if (t < NB) block_sums[t] = sums[t] - v;   // exclusive
}

// ---------------- stage 3 — write row_start & cursor ----------------------
__global__ __launch_bounds__(256) void scan_write(
    const int* __restrict__ cnt, const int* __restrict__ block_sums,
    int* __restrict__ row_start, int* __restrict__ cursor, int N)
{
    __shared__ int lsum[256];
    const int t = threadIdx.x;
    const int base = blockIdx.x * 1024 + t * 4;
    int v0 = 0, v1 = 0, v2 = 0, v3 = 0;
    if (base + 3 < N) {
        int4 v = *(const int4*)&cnt[base];
        v0 = v.x; v1 = v.y; v2 = v.z; v3 = v.w;
    } else {
        if (base     < N) v0 = cnt[base];
        if (base + 1 < N) v1 = cnt[base + 1];
        if (base + 2 < N) v2 = cnt[base + 2];
        if (base + 3 < N) v3 = cnt[base + 3];
    }
    const int s = v0 + v1 + v2 + v3;
    lsum[t] = s;
    __syncthreads();
    for (int off = 1; off < 256; off <<= 1) {
        int u = (t >= off) ? lsum[t - off] : 0;
        __syncthreads();
        lsum[t] += u;
        __syncthreads();
    }
    int p0 = lsum[t] - s + block_sums[blockIdx.x];
    int p1 = p0 + v0, p2 = p1 + v1, p3 = p2 + v2;
    if (base + 3 < N) {
        int4 r = make_int4(p0, p1, p2, p3);
        *(int4*)&row_start[base] = r;
        *(int4*)&cursor[base]    = r;
    } else {
        if (base     < N) { row_start[base]     = p0; cursor[base]     = p0; }
        if (base + 1 < N) { row_start[base + 1] = p1; cursor[base + 1] = p1; }
        if (base + 2 < N) { row_start[base + 2] = p2; cursor[base + 2] = p2; }
        if (base + 3 < N) { row_start[base + 3] = p3; cursor[base + 3] = p3; }
    }
}

// ---------------- CSR fill: csr_src[cursor[d]++] = s -----------------------
__global__ void fill_kernel(const int* __restrict__ src,
                            const int* __restrict__ dst,
                            int* __restrict__ cursor,
                            int* __restrict__ csr_src, int E)
{
    int t = blockIdx.x * blockDim.x + threadIdx.x;
    if (t < E) {
        int pos = atomicAdd(&cursor[dst[t]], 1);
        csr_src[pos] = src[t];
    }
}

// ---------------- dual GEMM:  Y = A@Wl,  C = A@Wr + b ----------------
template <int K, int F, bool RELU>
__global__ __launch_bounds__(256) void gemm_dual(
    const float* __restrict__ A,
    const float* __restrict__ Wl, const float* __restrict__ Wr,
    const float* __restrict__ b,
    float* __restrict__ Y, float* __restrict__ C, int N)
{
    constexpr int F2   = 2 * F;
    constexpr int JG   = F2 / 4;
    constexpr int NPB  = 2 * 256 / JG;
    constexpr int APAD = K + 4;

    __shared__ float Wsm[K * F2];
    __shared__ float Asm[NPB * APAD];

    const int tid = threadIdx.x;

    for (int i = tid; i < K * F2; i += 256) {
        int k = i / F2, j = i % F2;
        Wsm[i] = (j < F) ? Wl[k * F + j] : Wr[k * F + (j - F)];
    }

    const int node0 = blockIdx.x * NPB;
    constexpr int NF4 = NPB * K / 4;
    for (int f4 = tid; f4 < NF4; f4 += 256) {
        int n  = f4 / (K / 4);
        int kq = f4 % (K / 4);
        int gn = node0 + n;
        float4 v = make_float4(0.f, 0.f, 0.f, 0.f);
        if (gn < N) v = *(const float4*)&A[(size_t)gn * K + kq * 4];
        if (RELU) {
            v.x = fmaxf(v.x, 0.f); v.y = fmaxf(v.y, 0.f);
            v.z = fmaxf(v.z, 0.f); v.w = fmaxf(v.w, 0.f);
        }
        *(float4*)&Asm[n * APAD + kq * 4] = v;
    }
    __syncthreads();

    const int j0 = (tid % JG) * 4;
    const int n0 = (tid / JG) * 2;

    float acc[2][4] = {};
    #pragma unroll 4
    for (int k = 0; k < K; k += 4) {
        float4 a0 = *(const float4*)&Asm[n0 * APAD + k];
        float4 a1 = *(const float4*)&Asm[(n0 + 1) * APAD + k];
        #pragma unroll
        for (int kk = 0; kk < 4; ++kk) {
            float4 wv = *(const float4*)&Wsm[(k + kk) * F2 + j0];
            float av0 = ((const float*)&a0)[kk];
            float av1 = ((const float*)&a1)[kk];
            acc[0][0] += av0 * wv.x; acc[0][1] += av0 * wv.y;
            acc[0][2] += av0 * wv.z; acc[0][3] += av0 * wv.w;
            acc[1][0] += av1 * wv.x; acc[1][1] += av1 * wv.y;
            acc[1][2] += av1 * wv.z; acc[1][3] += av1 * wv.w;
        }
    }

    const bool isY = (j0 < F);
    const int  jj  = isY ? j0 : (j0 - F);
    float4 bias = make_float4(0.f, 0.f, 0.f, 0.f);
    if (!isY) bias = *(const float4*)&b[jj];
    float* dstp = isY ? Y : C;
    #pragma unroll
    for (int m = 0; m < 2; ++m) {
        int gn = node0 + n0 + m;
        if (gn < N) {
            float4 r;
            r.x = acc[m][0] + bias.x;
            r.y = acc[m][1] + bias.y;
            r.z = acc[m][2] + bias.z;
            r.w = acc[m][3] + bias.w;
            *(float4*)&dstp[(size_t)gn * F + jj] = r;
        }
    }
}

// ---------------- CSR gather:  C[i] += (1/deg_i) * sum_{j in in(i)} Y[j] ---
template <int F>
__global__ void gather_kernel(const int* __restrict__ row_start,
                              const int* __restrict__ row_end,
                              const int* __restrict__ csr_src,
                              const float* __restrict__ Y,
                              float* __restrict__ C, int N)
{
    constexpr int TPN = F / 4;
    int gid  = blockIdx.x * blockDim.x + threadIdx.x;
    int node = gid / TPN;
    int q    = gid % TPN;
    if (node >= N) return;

    int start = row_start[node];
    int end   = row_end[node];
    float w   = 1.0f / fmaxf((float)(end - start), 1.0f);

    float4 acc = make_float4(0.f, 0.f, 0.f, 0.f);
    for (int j = start; j < end; ++j) {
        int s = csr_src[j];
        float4 v = *(const float4*)&Y[(size_t)s * F + q * 4];
        acc.x += v.x; acc.y += v.y; acc.z += v.z; acc.w += v.w;
    }

    float* o = &C[(size_t)node * F + q * 4];
    float4 c = *(const float4*)o;
    c.x += acc.x * w; c.y += acc.y * w;
    c.z += acc.z * w; c.w += acc.w * w;
    *(float4*)o = c;
}

// ---------------- final: out = relu(c2) @ Wfc + bfc ----------------
__global__ void final_kernel(const float* __restrict__ c2,
                             const float* __restrict__ Wfc,
                             const float* __restrict__ bfc,
                             float* __restrict__ out, int N)
{
    int t = blockIdx.x * blockDim.x + threadIdx.x;
    if (t >= N) return;
    float o0 = bfc[0], o1 = bfc[1];
    #pragma unroll
    for (int c = 0; c < 16; ++c) {
        float h = fmaxf(c2[(size_t)t * 16 + c], 0.f);
        o0 += h * Wfc[c * 2 + 0];
        o1 += h * Wfc[c * 2 + 1];
    }
    ((float2*)out)[t] = make_float2(o0, o1);
}

extern "C" void kernel_launch(void* const* d_in, const int* in_sizes, int n_in,
                              void* d_out, int out_size, void* d_ws, size_t ws_size,
                              hipStream_t stream)
{
    const float* x   = (const float*)d_in[0];
    const int*   ei  = (const int*)d_in[1];   // int32 (JAX default)
    const float* W1l = (const float*)d_in[2];
    const float* b1  = (const float*)d_in[3];
    const float* W1r = (const float*)d_in[4];
    const float* W2l = (const float*)d_in[5];
    const float* b2  = (const float*)d_in[6];
    const float* W2r = (const float*)d_in[7];
    const float* Wfc = (const float*)d_in[8];
    const float* bfc = (const float*)d_in[9];
    float* out = (float*)d_out;

    const int N = in_sizes[0] / 128;
    const int E = in_sizes[1] / 2;
    const int* src = ei;
    const int* dst = ei + E;

    const int NB = (N + 1023) / 1024;   // scan blocks (98 for N=100000)

    // workspace layout (≈33 MB): ints first, then float buffers.
    int*   cnt        = (int*)d_ws;                 // N
    int*   row_start  = cnt + N;                    // N
    int*   cursor     = row_start + N;              // N (post-fill: row END)
    int*   block_sums = cursor + N;                 // NB (<=256)
    int*   csr_src    = block_sums + 256;           // E
    float* y1         = (float*)(csr_src + E);      // N*32
    float* c1         = y1 + (size_t)N * 32;        // N*32
    float* y2         = y1;                         // N*16 (overlays dead y1)
    float* c2         = y1 + (size_t)N * 16;        // N*16

    // ---- build CSR ----
    hipMemsetAsync(cnt, 0, (size_t)N * sizeof(int), stream);
    hist_kernel<<<(E + TPB - 1) / TPB, TPB, 0, stream>>>(dst, cnt, E);
    scan_partial<<<NB, 256, 0, stream>>>(cnt, block_sums, N);
    scan_blocksums<<<1, 256, 0, stream>>>(block_sums, NB);
    scan_write<<<NB, 256, 0, stream>>>(cnt, block_sums, row_start, cursor, N);
    fill_kernel<<<(E + TPB - 1) / TPB, TPB, 0, stream>>>(src, dst, cursor, csr_src, E);

    // ---- layer 1: y1 = x@W1l, c1 = x@W1r + b1; c1 += mean(y1[in(i)]) ----
    gemm_dual<128, 32, false><<<(N + 31) / 32, TPB, 0, stream>>>(
        x, W1l, W1r, b1, y1, c1, N);
    gather_kernel<32><<<(N * 8 + TPB - 1) / TPB, TPB, 0, stream>>>(
        row_start, cursor, csr_src, y1, c1, N);

    // ---- layer 2: y2 = relu(c1)@W2l, c2 = relu(c1)@W2r + b2; c2 += mean ----
    gemm_dual<32, 16, true><<<(N + 63) / 64, TPB, 0, stream>>>(
        c1, W2l, W2r, b2, y2, c2, N);
    gather_kernel<16><<<(N * 4 + TPB - 1) / TPB, TPB, 0, stream>>>(
        row_start, cursor, csr_src, y2, c2, N);

    // ---- final ----
    final_kernel<<<(N + TPB - 1) / TPB, TPB, 0, stream>>>(c2, Wfc, bfc, out, N);
}

// Round 5
// 274.921 us; speedup vs baseline: 4.3543x; 1.4539x over previous
//
#include <hip/hip_runtime.h>

#define TPB 256
#define BK_SHIFT 7
#define BK_SIZE 128
#define NBK_MAX 800     // >= ceil(100000/128)=782
#define EPT 32          // edges per thread in bin_scatter chunks

// ---------------- bucket histogram (LDS-privatized) -----------------------
__global__ __launch_bounds__(256) void hist_buckets(
    const int* __restrict__ dst, int* __restrict__ bcnt, int E, int NBK)
{
    __shared__ int h[NBK_MAX];
    const int t = threadIdx.x;
    for (int i = t; i < NBK; i += 256) h[i] = 0;
    __syncthreads();
    for (int e = blockIdx.x * blockDim.x + t; e < E; e += gridDim.x * blockDim.x)
        atomicAdd(&h[dst[e] >> BK_SHIFT], 1);
    __syncthreads();
    for (int i = t; i < NBK; i += 256)
        if (h[i]) atomicAdd(&bcnt[i], h[i]);
}

// ---------------- scan of bucket counts (one block, NBK<=1024) ------------
__global__ __launch_bounds__(1024) void scan_buckets(
    const int* __restrict__ bcnt, int* __restrict__ bbase,
    int* __restrict__ gcursor, int NBK)
{
    __shared__ int s[1024];
    const int t = threadIdx.x;
    int v = (t < NBK) ? bcnt[t] : 0;
    s[t] = v;
    __syncthreads();
    for (int off = 1; off < 1024; off <<= 1) {
        int u = (t >= off) ? s[t - off] : 0;
        __syncthreads();
        s[t] += u;
        __syncthreads();
    }
    if (t < NBK) {
        int excl = s[t] - v;
        bbase[t]   = excl;
        gcursor[t] = excl;
    }
}

// ---------------- bin scatter: pack edges into bucket-ordered pk[] --------
// Per block: local bucket counts -> one global atomic reserve per bucket ->
// contiguous writes per (block,bucket). pk = (src<<7) | (dst & 127).
__global__ __launch_bounds__(256) void bin_scatter(
    const int* __restrict__ src, const int* __restrict__ dst,
    int* __restrict__ gcursor, int* __restrict__ pk, int E, int NBK)
{
    __shared__ int lcnt[NBK_MAX];
    __shared__ int lbase[NBK_MAX];
    __shared__ int lrank[NBK_MAX];
    const int t = threadIdx.x;
    const int e0 = blockIdx.x * (256 * EPT);

    for (int i = t; i < NBK; i += 256) { lcnt[i] = 0; lrank[i] = 0; }
    __syncthreads();

    #pragma unroll 4
    for (int k = 0; k < EPT; ++k) {
        int e = e0 + k * 256 + t;
        if (e < E) atomicAdd(&lcnt[dst[e] >> BK_SHIFT], 1);
    }
    __syncthreads();

    for (int i = t; i < NBK; i += 256) {
        int c = lcnt[i];
        if (c) lbase[i] = atomicAdd(&gcursor[i], c);
    }
    __syncthreads();

    #pragma unroll 4
    for (int k = 0; k < EPT; ++k) {
        int e = e0 + k * 256 + t;
        if (e < E) {
            int d = dst[e], s = src[e];
            int b = d >> BK_SHIFT;
            int r = atomicAdd(&lrank[b], 1);
            pk[lbase[b] + r] = (s << BK_SHIFT) | (d & (BK_SIZE - 1));
        }
    }
}

// ---------------- per-bucket counting sort -> exact CSR -------------------
// Block b owns bucket b: sorts its packed entries by local node id, writes
// csr_src + row_start/row_end. All scatter stays in an ~8KB L2 window.
__global__ __launch_bounds__(256) void bucket_csr(
    const int* __restrict__ pk, const int* __restrict__ bbase,
    const int* __restrict__ bcnt,
    int* __restrict__ csr_src, int* __restrict__ row_start,
    int* __restrict__ row_end, int N)
{
    __shared__ int lcnt[BK_SIZE];
    __shared__ int s[BK_SIZE];
    __shared__ int wcur[BK_SIZE];
    const int t = threadIdx.x;
    const int b = blockIdx.x;
    const int base = bbase[b];
    const int cnt  = bcnt[b];
    const int node0 = b * BK_SIZE;

    if (t < BK_SIZE) lcnt[t] = 0;
    __syncthreads();

    for (int j = t; j < cnt; j += 256)
        atomicAdd(&lcnt[pk[base + j] & (BK_SIZE - 1)], 1);
    __syncthreads();

    // inclusive scan of lcnt[128]
    if (t < BK_SIZE) s[t] = lcnt[t];
    __syncthreads();
    for (int off = 1; off < BK_SIZE; off <<= 1) {
        int u = (t < BK_SIZE && t >= off) ? s[t - off] : 0;
        __syncthreads();
        if (t < BK_SIZE) s[t] += u;
        __syncthreads();
    }
    if (t < BK_SIZE) {
        int excl = s[t] - lcnt[t];
        wcur[t] = excl;
        int node = node0 + t;
        if (node < N) {
            row_start[node] = base + excl;
            row_end[node]   = base + s[t];
        }
    }
    __syncthreads();

    for (int j = t; j < cnt; j += 256) {
        int v = pk[base + j];
        int d = v & (BK_SIZE - 1);
        int pos = atomicAdd(&wcur[d], 1);
        csr_src[base + pos] = v >> BK_SHIFT;
    }
}

// ---------------- dual GEMM:  Y = A@Wl,  C = A@Wr + b ----------------
template <int K, int F, bool RELU>
__global__ __launch_bounds__(256) void gemm_dual(
    const float* __restrict__ A,
    const float* __restrict__ Wl, const float* __restrict__ Wr,
    const float* __restrict__ b,
    float* __restrict__ Y, float* __restrict__ C, int N)
{
    constexpr int F2   = 2 * F;
    constexpr int JG   = F2 / 4;
    constexpr int NPB  = 2 * 256 / JG;
    constexpr int APAD = K + 4;

    __shared__ float Wsm[K * F2];
    __shared__ float Asm[NPB * APAD];

    const int tid = threadIdx.x;

    for (int i = tid; i < K * F2; i += 256) {
        int k = i / F2, j = i % F2;
        Wsm[i] = (j < F) ? Wl[k * F + j] : Wr[k * F + (j - F)];
    }

    const int node0 = blockIdx.x * NPB;
    constexpr int NF4 = NPB * K / 4;
    for (int f4 = tid; f4 < NF4; f4 += 256) {
        int n  = f4 / (K / 4);
        int kq = f4 % (K / 4);
        int gn = node0 + n;
        float4 v = make_float4(0.f, 0.f, 0.f, 0.f);
        if (gn < N) v = *(const float4*)&A[(size_t)gn * K + kq * 4];
        if (RELU) {
            v.x = fmaxf(v.x, 0.f); v.y = fmaxf(v.y, 0.f);
            v.z = fmaxf(v.z, 0.f); v.w = fmaxf(v.w, 0.f);
        }
        *(float4*)&Asm[n * APAD + kq * 4] = v;
    }
    __syncthreads();

    const int j0 = (tid % JG) * 4;
    const int n0 = (tid / JG) * 2;

    float acc[2][4] = {};
    #pragma unroll 4
    for (int k = 0; k < K; k += 4) {
        float4 a0 = *(const float4*)&Asm[n0 * APAD + k];
        float4 a1 = *(const float4*)&Asm[(n0 + 1) * APAD + k];
        #pragma unroll
        for (int kk = 0; kk < 4; ++kk) {
            float4 wv = *(const float4*)&Wsm[(k + kk) * F2 + j0];
            float av0 = ((const float*)&a0)[kk];
            float av1 = ((const float*)&a1)[kk];
            acc[0][0] += av0 * wv.x; acc[0][1] += av0 * wv.y;
            acc[0][2] += av0 * wv.z; acc[0][3] += av0 * wv.w;
            acc[1][0] += av1 * wv.x; acc[1][1] += av1 * wv.y;
            acc[1][2] += av1 * wv.z; acc[1][3] += av1 * wv.w;
        }
    }

    const bool isY = (j0 < F);
    const int  jj  = isY ? j0 : (j0 - F);
    float4 bias = make_float4(0.f, 0.f, 0.f, 0.f);
    if (!isY) bias = *(const float4*)&b[jj];
    float* dstp = isY ? Y : C;
    #pragma unroll
    for (int m = 0; m < 2; ++m) {
        int gn = node0 + n0 + m;
        if (gn < N) {
            float4 r;
            r.x = acc[m][0] + bias.x;
            r.y = acc[m][1] + bias.y;
            r.z = acc[m][2] + bias.z;
            r.w = acc[m][3] + bias.w;
            *(float4*)&dstp[(size_t)gn * F + jj] = r;
        }
    }
}

// ---------------- CSR gather:  C[i] += (1/deg_i) * sum_{j in in(i)} Y[j] ---
template <int F>
__global__ void gather_kernel(const int* __restrict__ row_start,
                              const int* __restrict__ row_end,
                              const int* __restrict__ csr_src,
                              const float* __restrict__ Y,
                              float* __restrict__ C, int N)
{
    constexpr int TPN = F / 4;
    int gid  = blockIdx.x * blockDim.x + threadIdx.x;
    int node = gid / TPN;
    int q    = gid % TPN;
    if (node >= N) return;

    int start = row_start[node];
    int end   = row_end[node];
    float w   = 1.0f / fmaxf((float)(end - start), 1.0f);

    float4 acc = make_float4(0.f, 0.f, 0.f, 0.f);
    for (int j = start; j < end; ++j) {
        int s = csr_src[j];
        float4 v = *(const float4*)&Y[(size_t)s * F + q * 4];
        acc.x += v.x; acc.y += v.y; acc.z += v.z; acc.w += v.w;
    }

    float* o = &C[(size_t)node * F + q * 4];
    float4 c = *(const float4*)o;
    c.x += acc.x * w; c.y += acc.y * w;
    c.z += acc.z * w; c.w += acc.w * w;
    *(float4*)o = c;
}

// ---------------- final: out = relu(c2) @ Wfc + bfc ----------------
__global__ void final_kernel(const float* __restrict__ c2,
                             const float* __restrict__ Wfc,
                             const float* __restrict__ bfc,
                             float* __restrict__ out, int N)
{
    int t = blockIdx.x * blockDim.x + threadIdx.x;
    if (t >= N) return;
    float o0 = bfc[0], o1 = bfc[1];
    #pragma unroll
    for (int c = 0; c < 16; ++c) {
        float h = fmaxf(c2[(size_t)t * 16 + c], 0.f);
        o0 += h * Wfc[c * 2 + 0];
        o1 += h * Wfc[c * 2 + 1];
    }
    ((float2*)out)[t] = make_float2(o0, o1);
}

extern "C" void kernel_launch(void* const* d_in, const int* in_sizes, int n_in,
                              void* d_out, int out_size, void* d_ws, size_t ws_size,
                              hipStream_t stream)
{
    const float* x   = (const float*)d_in[0];
    const int*   ei  = (const int*)d_in[1];   // int32 (JAX default)
    const float* W1l = (const float*)d_in[2];
    const float* b1  = (const float*)d_in[3];
    const float* W1r = (const float*)d_in[4];
    const float* W2l = (const float*)d_in[5];
    const float* b2  = (const float*)d_in[6];
    const float* W2r = (const float*)d_in[7];
    const float* Wfc = (const float*)d_in[8];
    const float* bfc = (const float*)d_in[9];
    float* out = (float*)d_out;

    const int N = in_sizes[0] / 128;
    const int E = in_sizes[1] / 2;
    const int* src = ei;
    const int* dst = ei + E;

    const int NBK = (N + BK_SIZE - 1) / BK_SIZE;   // 782

    // workspace layout: ints, then float buffers. pk aliases y1 (dead before gemm1).
    int*   bucket_cnt  = (int*)d_ws;                // NBK
    int*   bucket_base = bucket_cnt + NBK_MAX;      // NBK
    int*   gcursor     = bucket_base + NBK_MAX;     // NBK
    int*   row_start   = gcursor + NBK_MAX;         // N
    int*   row_end     = row_start + N;             // N
    int*   csr_src     = row_end + N;               // E
    float* y1          = (float*)(csr_src + E);     // N*32
    float* c1          = y1 + (size_t)N * 32;       // N*32
    float* y2          = y1;                        // N*16 (overlays dead y1)
    float* c2          = y1 + (size_t)N * 16;       // N*16
    int*   pk          = (int*)y1;                  // E (dead before gemm1 writes y1)

    // ---- build CSR (bucketed) ----
    hipMemsetAsync(bucket_cnt, 0, (size_t)NBK * sizeof(int), stream);
    hist_buckets<<<196, 256, 0, stream>>>(dst, bucket_cnt, E, NBK);
    scan_buckets<<<1, 1024, 0, stream>>>(bucket_cnt, bucket_base, gcursor, NBK);
    {
        int nb = (E + 256 * EPT - 1) / (256 * EPT);
        bin_scatter<<<nb, 256, 0, stream>>>(src, dst, gcursor, pk, E, NBK);
    }
    bucket_csr<<<NBK, 256, 0, stream>>>(pk, bucket_base, bucket_cnt,
                                        csr_src, row_start, row_end, N);

    // ---- layer 1: y1 = x@W1l, c1 = x@W1r + b1; c1 += mean(y1[in(i)]) ----
    gemm_dual<128, 32, false><<<(N + 31) / 32, TPB, 0, stream>>>(
        x, W1l, W1r, b1, y1, c1, N);
    gather_kernel<32><<<(N * 8 + TPB - 1) / TPB, TPB, 0, stream>>>(
        row_start, row_end, csr_src, y1, c1, N);

    // ---- layer 2: y2 = relu(c1)@W2l, c2 = relu(c1)@W2r + b2; c2 += mean ----
    gemm_dual<32, 16, true><<<(N + 63) / 64, TPB, 0, stream>>>(
        c1, W2l, W2r, b2, y2, c2, N);
    gather_kernel<16><<<(N * 4 + TPB - 1) / TPB, TPB, 0, stream>>>(
        row_start, row_end, csr_src, y2, c2, N);

    // ---- final ----
    final_kernel<<<(N + TPB - 1) / TPB, TPB, 0, stream>>>(c2, Wfc, bfc, out, N);
}

// Round 6
// 269.374 us; speedup vs baseline: 4.4439x; 1.0206x over previous
//
#include <hip/hip_runtime.h>

#define TPB 256
#define BK_SHIFT 7
#define BK_SIZE 128
#define NBK_MAX 800     // >= ceil(100000/128)=782
#define EPT 32          // edges per thread in bin_scatter chunks

// ---------------- bucket histogram (LDS-privatized, int4 loads) -----------
__global__ __launch_bounds__(256) void hist_buckets(
    const int* __restrict__ dst, int* __restrict__ bcnt, int E, int NBK)
{
    __shared__ int h[NBK_MAX];
    const int t = threadIdx.x;
    for (int i = t; i < NBK; i += 256) h[i] = 0;
    __syncthreads();
    const int E4 = E >> 2;
    for (int e4 = blockIdx.x * blockDim.x + t; e4 < E4; e4 += gridDim.x * blockDim.x) {
        int4 d = ((const int4*)dst)[e4];
        atomicAdd(&h[d.x >> BK_SHIFT], 1);
        atomicAdd(&h[d.y >> BK_SHIFT], 1);
        atomicAdd(&h[d.z >> BK_SHIFT], 1);
        atomicAdd(&h[d.w >> BK_SHIFT], 1);
    }
    // tail
    if (blockIdx.x == 0) {
        for (int e = E4 * 4 + t; e < E; e += 256)
            atomicAdd(&h[dst[e] >> BK_SHIFT], 1);
    }
    __syncthreads();
    for (int i = t; i < NBK; i += 256)
        if (h[i]) atomicAdd(&bcnt[i], h[i]);
}

// ---------------- scan of bucket counts (one block, NBK<=1024) ------------
__global__ __launch_bounds__(1024) void scan_buckets(
    const int* __restrict__ bcnt, int* __restrict__ bbase,
    int* __restrict__ gcursor, int NBK)
{
    __shared__ int s[1024];
    const int t = threadIdx.x;
    int v = (t < NBK) ? bcnt[t] : 0;
    s[t] = v;
    __syncthreads();
    for (int off = 1; off < 1024; off <<= 1) {
        int u = (t >= off) ? s[t - off] : 0;
        __syncthreads();
        s[t] += u;
        __syncthreads();
    }
    if (t < NBK) {
        int excl = s[t] - v;
        bbase[t]   = excl;
        gcursor[t] = excl;
    }
}

// ---------------- bin scatter: pack edges into bucket-ordered pk[] --------
__global__ __launch_bounds__(256) void bin_scatter(
    const int* __restrict__ src, const int* __restrict__ dst,
    int* __restrict__ gcursor, int* __restrict__ pk, int E, int NBK)
{
    __shared__ int lcnt[NBK_MAX];
    __shared__ int lbase[NBK_MAX];
    __shared__ int lrank[NBK_MAX];
    const int t = threadIdx.x;
    const int e0 = blockIdx.x * (256 * EPT);

    for (int i = t; i < NBK; i += 256) { lcnt[i] = 0; lrank[i] = 0; }
    __syncthreads();

    #pragma unroll 4
    for (int k = 0; k < EPT; ++k) {
        int e = e0 + k * 256 + t;
        if (e < E) atomicAdd(&lcnt[dst[e] >> BK_SHIFT], 1);
    }
    __syncthreads();

    for (int i = t; i < NBK; i += 256) {
        int c = lcnt[i];
        if (c) lbase[i] = atomicAdd(&gcursor[i], c);
    }
    __syncthreads();

    #pragma unroll 4
    for (int k = 0; k < EPT; ++k) {
        int e = e0 + k * 256 + t;
        if (e < E) {
            int d = dst[e], s = src[e];
            int b = d >> BK_SHIFT;
            int r = atomicAdd(&lrank[b], 1);
            pk[lbase[b] + r] = (s << BK_SHIFT) | (d & (BK_SIZE - 1));
        }
    }
}

// ---------------- per-bucket counting sort -> exact CSR -------------------
__global__ __launch_bounds__(256) void bucket_csr(
    const int* __restrict__ pk, const int* __restrict__ bbase,
    const int* __restrict__ bcnt,
    int* __restrict__ csr_src, int* __restrict__ row_start,
    int* __restrict__ row_end, int N)
{
    __shared__ int lcnt[BK_SIZE];
    __shared__ int s[BK_SIZE];
    __shared__ int wcur[BK_SIZE];
    const int t = threadIdx.x;
    const int b = blockIdx.x;
    const int base = bbase[b];
    const int cnt  = bcnt[b];
    const int node0 = b * BK_SIZE;

    if (t < BK_SIZE) lcnt[t] = 0;
    __syncthreads();

    for (int j = t; j < cnt; j += 256)
        atomicAdd(&lcnt[pk[base + j] & (BK_SIZE - 1)], 1);
    __syncthreads();

    if (t < BK_SIZE) s[t] = lcnt[t];
    __syncthreads();
    for (int off = 1; off < BK_SIZE; off <<= 1) {
        int u = (t < BK_SIZE && t >= off) ? s[t - off] : 0;
        __syncthreads();
        if (t < BK_SIZE) s[t] += u;
        __syncthreads();
    }
    if (t < BK_SIZE) {
        int excl = s[t] - lcnt[t];
        wcur[t] = excl;
        int node = node0 + t;
        if (node < N) {
            row_start[node] = base + excl;
            row_end[node]   = base + s[t];
        }
    }
    __syncthreads();

    for (int j = t; j < cnt; j += 256) {
        int v = pk[base + j];
        int d = v & (BK_SIZE - 1);
        int pos = atomicAdd(&wcur[d], 1);
        csr_src[base + pos] = v >> BK_SHIFT;
    }
}

// ---------------- dual GEMM:  Y = A@Wl,  C = A@Wr + b ----------------
// 4 nodes x 4 outputs per thread (16 acc): 16 FMA per ds_read_b128.
template <int K, int F, bool RELU>
__global__ __launch_bounds__(256) void gemm_dual(
    const float* __restrict__ A,
    const float* __restrict__ Wl, const float* __restrict__ Wr,
    const float* __restrict__ b,
    float* __restrict__ Y, float* __restrict__ C, int N)
{
    constexpr int F2   = 2 * F;
    constexpr int JG   = F2 / 4;        // j-groups (16 for L1, 8 for L2)
    constexpr int NG   = 256 / JG;      // node-groups per block
    constexpr int NPB  = NG * 4;        // nodes per block (64 L1, 128 L2)
    constexpr int APAD = K + 4;

    __shared__ float Wsm[K * F2];       // 32 KB (L1) / 4 KB (L2)
    __shared__ float Asm[NPB * APAD];   // 33.8 KB (L1) / 18.4 KB (L2)

    const int tid = threadIdx.x;

    for (int i = tid; i < K * F2; i += 256) {
        int k = i / F2, j = i % F2;
        Wsm[i] = (j < F) ? Wl[k * F + j] : Wr[k * F + (j - F)];
    }

    const int node0 = blockIdx.x * NPB;
    constexpr int NF4 = NPB * K / 4;
    for (int f4 = tid; f4 < NF4; f4 += 256) {
        int n  = f4 / (K / 4);
        int kq = f4 % (K / 4);
        int gn = node0 + n;
        float4 v = make_float4(0.f, 0.f, 0.f, 0.f);
        if (gn < N) v = *(const float4*)&A[(size_t)gn * K + kq * 4];
        if (RELU) {
            v.x = fmaxf(v.x, 0.f); v.y = fmaxf(v.y, 0.f);
            v.z = fmaxf(v.z, 0.f); v.w = fmaxf(v.w, 0.f);
        }
        *(float4*)&Asm[n * APAD + kq * 4] = v;
    }
    __syncthreads();

    const int j0 = (tid % JG) * 4;
    const int n0 = (tid / JG) * 4;

    float acc[4][4] = {};
    #pragma unroll 2
    for (int k = 0; k < K; k += 4) {
        float4 a0 = *(const float4*)&Asm[(n0 + 0) * APAD + k];
        float4 a1 = *(const float4*)&Asm[(n0 + 1) * APAD + k];
        float4 a2 = *(const float4*)&Asm[(n0 + 2) * APAD + k];
        float4 a3 = *(const float4*)&Asm[(n0 + 3) * APAD + k];
        #pragma unroll
        for (int kk = 0; kk < 4; ++kk) {
            float4 wv = *(const float4*)&Wsm[(k + kk) * F2 + j0];
            float av0 = ((const float*)&a0)[kk];
            float av1 = ((const float*)&a1)[kk];
            float av2 = ((const float*)&a2)[kk];
            float av3 = ((const float*)&a3)[kk];
            acc[0][0] += av0 * wv.x; acc[0][1] += av0 * wv.y;
            acc[0][2] += av0 * wv.z; acc[0][3] += av0 * wv.w;
            acc[1][0] += av1 * wv.x; acc[1][1] += av1 * wv.y;
            acc[1][2] += av1 * wv.z; acc[1][3] += av1 * wv.w;
            acc[2][0] += av2 * wv.x; acc[2][1] += av2 * wv.y;
            acc[2][2] += av2 * wv.z; acc[2][3] += av2 * wv.w;
            acc[3][0] += av3 * wv.x; acc[3][1] += av3 * wv.y;
            acc[3][2] += av3 * wv.z; acc[3][3] += av3 * wv.w;
        }
    }

    const bool isY = (j0 < F);
    const int  jj  = isY ? j0 : (j0 - F);
    float4 bias = make_float4(0.f, 0.f, 0.f, 0.f);
    if (!isY) bias = *(const float4*)&b[jj];
    float* dstp = isY ? Y : C;
    #pragma unroll
    for (int m = 0; m < 4; ++m) {
        int gn = node0 + n0 + m;
        if (gn < N) {
            float4 r;
            r.x = acc[m][0] + bias.x;
            r.y = acc[m][1] + bias.y;
            r.z = acc[m][2] + bias.z;
            r.w = acc[m][3] + bias.w;
            *(float4*)&dstp[(size_t)gn * F + jj] = r;
        }
    }
}

// ---------------- CSR gather (layer 1):  C[i] += mean Y[in(i)] ------------
template <int F>
__global__ void gather_kernel(const int* __restrict__ row_start,
                              const int* __restrict__ row_end,
                              const int* __restrict__ csr_src,
                              const float* __restrict__ Y,
                              float* __restrict__ C, int N)
{
    constexpr int TPN = F / 4;
    int gid  = blockIdx.x * blockDim.x + threadIdx.x;
    int node = gid / TPN;
    int q    = gid % TPN;
    if (node >= N) return;

    int start = row_start[node];
    int end   = row_end[node];
    float w   = 1.0f / fmaxf((float)(end - start), 1.0f);

    float4 acc = make_float4(0.f, 0.f, 0.f, 0.f);
    for (int j = start; j < end; ++j) {
        int s = csr_src[j];
        float4 v = *(const float4*)&Y[(size_t)s * F + q * 4];
        acc.x += v.x; acc.y += v.y; acc.z += v.z; acc.w += v.w;
    }

    float* o = &C[(size_t)node * F + q * 4];
    float4 c = *(const float4*)o;
    c.x += acc.x * w; c.y += acc.y * w;
    c.z += acc.z * w; c.w += acc.w * w;
    *(float4*)o = c;
}

// ---------------- fused gather2 + final:  out = relu(c2 + mean)@Wfc + bfc -
// 4 threads per node (16 ch); shuffle-reduce the 2-wide output across lanes.
__global__ void gather_final(const int* __restrict__ row_start,
                             const int* __restrict__ row_end,
                             const int* __restrict__ csr_src,
                             const float* __restrict__ Y,   // y2 [N][16]
                             const float* __restrict__ c2,  // [N][16]
                             const float* __restrict__ Wfc, // [16][2]
                             const float* __restrict__ bfc, // [2]
                             float* __restrict__ out, int N)
{
    int gid  = blockIdx.x * blockDim.x + threadIdx.x;
    int node = gid / 4;
    int q    = gid % 4;
    if (node >= N) return;

    int start = row_start[node];
    int end   = row_end[node];
    float w   = 1.0f / fmaxf((float)(end - start), 1.0f);

    float4 acc = make_float4(0.f, 0.f, 0.f, 0.f);
    for (int j = start; j < end; ++j) {
        int s = csr_src[j];
        float4 v = *(const float4*)&Y[(size_t)s * 16 + q * 4];
        acc.x += v.x; acc.y += v.y; acc.z += v.z; acc.w += v.w;
    }

    float4 c = *(const float4*)&c2[(size_t)node * 16 + q * 4];
    float h0 = fmaxf(c.x + acc.x * w, 0.f);
    float h1 = fmaxf(c.y + acc.y * w, 0.f);
    float h2 = fmaxf(c.z + acc.z * w, 0.f);
    float h3 = fmaxf(c.w + acc.w * w, 0.f);

    const float* Wq = &Wfc[q * 8];   // rows q*4 .. q*4+3, 2 cols
    float o0 = h0 * Wq[0] + h1 * Wq[2] + h2 * Wq[4] + h3 * Wq[6];
    float o1 = h0 * Wq[1] + h1 * Wq[3] + h2 * Wq[5] + h3 * Wq[7];

    o0 += __shfl_xor(o0, 1); o0 += __shfl_xor(o0, 2);
    o1 += __shfl_xor(o1, 1); o1 += __shfl_xor(o1, 2);

    if (q == 0) ((float2*)out)[node] = make_float2(o0 + bfc[0], o1 + bfc[1]);
}

extern "C" void kernel_launch(void* const* d_in, const int* in_sizes, int n_in,
                              void* d_out, int out_size, void* d_ws, size_t ws_size,
                              hipStream_t stream)
{
    const float* x   = (const float*)d_in[0];
    const int*   ei  = (const int*)d_in[1];   // int32 (JAX default)
    const float* W1l = (const float*)d_in[2];
    const float* b1  = (const float*)d_in[3];
    const float* W1r = (const float*)d_in[4];
    const float* W2l = (const float*)d_in[5];
    const float* b2  = (const float*)d_in[6];
    const float* W2r = (const float*)d_in[7];
    const float* Wfc = (const float*)d_in[8];
    const float* bfc = (const float*)d_in[9];
    float* out = (float*)d_out;

    const int N = in_sizes[0] / 128;
    const int E = in_sizes[1] / 2;
    const int* src = ei;
    const int* dst = ei + E;

    const int NBK = (N + BK_SIZE - 1) / BK_SIZE;   // 782

    int*   bucket_cnt  = (int*)d_ws;                // NBK
    int*   bucket_base = bucket_cnt + NBK_MAX;      // NBK
    int*   gcursor     = bucket_base + NBK_MAX;     // NBK
    int*   row_start   = gcursor + NBK_MAX;         // N
    int*   row_end     = row_start + N;             // N
    int*   csr_src     = row_end + N;               // E
    float* y1          = (float*)(csr_src + E);     // N*32
    float* c1          = y1 + (size_t)N * 32;       // N*32
    float* y2          = y1;                        // N*16 (overlays dead y1)
    float* c2          = y1 + (size_t)N * 16;       // N*16
    int*   pk          = (int*)y1;                  // E (dead before gemm1 writes y1)

    // ---- build CSR (bucketed) ----
    hipMemsetAsync(bucket_cnt, 0, (size_t)NBK * sizeof(int), stream);
    hist_buckets<<<196, 256, 0, stream>>>(dst, bucket_cnt, E, NBK);
    scan_buckets<<<1, 1024, 0, stream>>>(bucket_cnt, bucket_base, gcursor, NBK);
    {
        int nb = (E + 256 * EPT - 1) / (256 * EPT);
        bin_scatter<<<nb, 256, 0, stream>>>(src, dst, gcursor, pk, E, NBK);
    }
    bucket_csr<<<NBK, 256, 0, stream>>>(pk, bucket_base, bucket_cnt,
                                        csr_src, row_start, row_end, N);

    // ---- layer 1: y1 = x@W1l, c1 = x@W1r + b1; c1 += mean(y1[in(i)]) ----
    gemm_dual<128, 32, false><<<(N + 63) / 64, TPB, 0, stream>>>(
        x, W1l, W1r, b1, y1, c1, N);
    gather_kernel<32><<<(N * 8 + TPB - 1) / TPB, TPB, 0, stream>>>(
        row_start, row_end, csr_src, y1, c1, N);

    // ---- layer 2: y2 = relu(c1)@W2l, c2 = relu(c1)@W2r + b2 ----
    gemm_dual<32, 16, true><<<(N + 127) / 128, TPB, 0, stream>>>(
        c1, W2l, W2r, b2, y2, c2, N);

    // ---- fused gather2 + final ----
    gather_final<<<(N * 4 + TPB - 1) / TPB, TPB, 0, stream>>>(
        row_start, row_end, csr_src, y2, c2, Wfc, bfc, out, N);
}

// Round 7
// 269.359 us; speedup vs baseline: 4.4442x; 1.0001x over previous
//
#include <hip/hip_runtime.h>

#define TPB 256
#define BK_SHIFT 7
#define BK_SIZE 128
#define NBK_MAX 800     // >= ceil(100000/128)=782
#define EPT 32          // edges per thread in bin_scatter chunks

// ---------------- bucket histogram (LDS-privatized, int4 loads) -----------
__global__ __launch_bounds__(256) void hist_buckets(
    const int* __restrict__ dst, int* __restrict__ bcnt, int E, int NBK)
{
    __shared__ int h[NBK_MAX];
    const int t = threadIdx.x;
    for (int i = t; i < NBK; i += 256) h[i] = 0;
    __syncthreads();
    const int E4 = E >> 2;
    for (int e4 = blockIdx.x * blockDim.x + t; e4 < E4; e4 += gridDim.x * blockDim.x) {
        int4 d = ((const int4*)dst)[e4];
        atomicAdd(&h[d.x >> BK_SHIFT], 1);
        atomicAdd(&h[d.y >> BK_SHIFT], 1);
        atomicAdd(&h[d.z >> BK_SHIFT], 1);
        atomicAdd(&h[d.w >> BK_SHIFT], 1);
    }
    if (blockIdx.x == 0) {
        for (int e = E4 * 4 + t; e < E; e += 256)
            atomicAdd(&h[dst[e] >> BK_SHIFT], 1);
    }
    __syncthreads();
    for (int i = t; i < NBK; i += 256)
        if (h[i]) atomicAdd(&bcnt[i], h[i]);
}

// ---------------- scan of bucket counts (one block, NBK<=1024) ------------
__global__ __launch_bounds__(1024) void scan_buckets(
    const int* __restrict__ bcnt, int* __restrict__ bbase,
    int* __restrict__ gcursor, int NBK)
{
    __shared__ int s[1024];
    const int t = threadIdx.x;
    int v = (t < NBK) ? bcnt[t] : 0;
    s[t] = v;
    __syncthreads();
    for (int off = 1; off < 1024; off <<= 1) {
        int u = (t >= off) ? s[t - off] : 0;
        __syncthreads();
        s[t] += u;
        __syncthreads();
    }
    if (t < NBK) {
        int excl = s[t] - v;
        bbase[t]   = excl;
        gcursor[t] = excl;
    }
}

// ---------------- bin scatter: pack edges into bucket-ordered pk[] --------
__global__ __launch_bounds__(256) void bin_scatter(
    const int* __restrict__ src, const int* __restrict__ dst,
    int* __restrict__ gcursor, int* __restrict__ pk, int E, int NBK)
{
    __shared__ int lcnt[NBK_MAX];
    __shared__ int lbase[NBK_MAX];
    __shared__ int lrank[NBK_MAX];
    const int t = threadIdx.x;
    const int e0 = blockIdx.x * (256 * EPT);

    for (int i = t; i < NBK; i += 256) { lcnt[i] = 0; lrank[i] = 0; }
    __syncthreads();

    #pragma unroll 4
    for (int k = 0; k < EPT; ++k) {
        int e = e0 + k * 256 + t;
        if (e < E) atomicAdd(&lcnt[dst[e] >> BK_SHIFT], 1);
    }
    __syncthreads();

    for (int i = t; i < NBK; i += 256) {
        int c = lcnt[i];
        if (c) lbase[i] = atomicAdd(&gcursor[i], c);
    }
    __syncthreads();

    #pragma unroll 4
    for (int k = 0; k < EPT; ++k) {
        int e = e0 + k * 256 + t;
        if (e < E) {
            int d = dst[e], s = src[e];
            int b = d >> BK_SHIFT;
            int r = atomicAdd(&lrank[b], 1);
            pk[lbase[b] + r] = (s << BK_SHIFT) | (d & (BK_SIZE - 1));
        }
    }
}

// ---------------- per-bucket counting sort -> exact CSR -------------------
__global__ __launch_bounds__(256) void bucket_csr(
    const int* __restrict__ pk, const int* __restrict__ bbase,
    const int* __restrict__ bcnt,
    int* __restrict__ csr_src, int* __restrict__ row_start,
    int* __restrict__ row_end, int N)
{
    __shared__ int lcnt[BK_SIZE];
    __shared__ int s[BK_SIZE];
    __shared__ int wcur[BK_SIZE];
    const int t = threadIdx.x;
    const int b = blockIdx.x;
    const int base = bbase[b];
    const int cnt  = bcnt[b];
    const int node0 = b * BK_SIZE;

    if (t < BK_SIZE) lcnt[t] = 0;
    __syncthreads();

    for (int j = t; j < cnt; j += 256)
        atomicAdd(&lcnt[pk[base + j] & (BK_SIZE - 1)], 1);
    __syncthreads();

    if (t < BK_SIZE) s[t] = lcnt[t];
    __syncthreads();
    for (int off = 1; off < BK_SIZE; off <<= 1) {
        int u = (t < BK_SIZE && t >= off) ? s[t - off] : 0;
        __syncthreads();
        if (t < BK_SIZE) s[t] += u;
        __syncthreads();
    }
    if (t < BK_SIZE) {
        int excl = s[t] - lcnt[t];
        wcur[t] = excl;
        int node = node0 + t;
        if (node < N) {
            row_start[node] = base + excl;
            row_end[node]   = base + s[t];
        }
    }
    __syncthreads();

    for (int j = t; j < cnt; j += 256) {
        int v = pk[base + j];
        int d = v & (BK_SIZE - 1);
        int pos = atomicAdd(&wcur[d], 1);
        csr_src[base + pos] = v >> BK_SHIFT;
    }
}

// ---------------- dual GEMM:  Y = A@Wl,  C = A@Wr + b ----------------
// A-tile in LDS (coalesced staging); W read directly from global (L1/L2-hot,
// shared by all blocks) -> small LDS footprint -> 4+ blocks/CU.
// 4 nodes x 4 outputs per thread.
template <int K, int F, bool RELU>
__global__ __launch_bounds__(256) void gemm_dual(
    const float* __restrict__ A,
    const float* __restrict__ Wl, const float* __restrict__ Wr,
    const float* __restrict__ b,
    float* __restrict__ Y, float* __restrict__ C, int N)
{
    constexpr int F2   = 2 * F;
    constexpr int JG   = F2 / 4;        // j-groups (16 for L1, 8 for L2)
    constexpr int NG   = 256 / JG;      // node-groups per block
    constexpr int NPB  = NG * 4;        // nodes per block (64 L1, 128 L2)
    constexpr int APAD = K + 4;

    __shared__ float Asm[NPB * APAD];   // 33.8 KB (L1) / 18.4 KB (L2)

    const int tid = threadIdx.x;

    const int node0 = blockIdx.x * NPB;
    constexpr int NF4 = NPB * K / 4;
    for (int f4 = tid; f4 < NF4; f4 += 256) {
        int n  = f4 / (K / 4);
        int kq = f4 % (K / 4);
        int gn = node0 + n;
        float4 v = make_float4(0.f, 0.f, 0.f, 0.f);
        if (gn < N) v = *(const float4*)&A[(size_t)gn * K + kq * 4];
        if (RELU) {
            v.x = fmaxf(v.x, 0.f); v.y = fmaxf(v.y, 0.f);
            v.z = fmaxf(v.z, 0.f); v.w = fmaxf(v.w, 0.f);
        }
        *(float4*)&Asm[n * APAD + kq * 4] = v;
    }
    __syncthreads();

    const int j0 = (tid % JG) * 4;
    const int n0 = (tid / JG) * 4;

    // uniform pointer select (no divergent branch in the hot loop)
    const bool  isY = (j0 < F);
    const int   jj  = isY ? j0 : (j0 - F);
    const float* Wb = isY ? Wl : Wr;

    float acc[4][4] = {};
    #pragma unroll 2
    for (int k = 0; k < K; k += 4) {
        float4 a0 = *(const float4*)&Asm[(n0 + 0) * APAD + k];
        float4 a1 = *(const float4*)&Asm[(n0 + 1) * APAD + k];
        float4 a2 = *(const float4*)&Asm[(n0 + 2) * APAD + k];
        float4 a3 = *(const float4*)&Asm[(n0 + 3) * APAD + k];
        #pragma unroll
        for (int kk = 0; kk < 4; ++kk) {
            float4 wv = *(const float4*)&Wb[(k + kk) * F + jj];
            float av0 = ((const float*)&a0)[kk];
            float av1 = ((const float*)&a1)[kk];
            float av2 = ((const float*)&a2)[kk];
            float av3 = ((const float*)&a3)[kk];
            acc[0][0] += av0 * wv.x; acc[0][1] += av0 * wv.y;
            acc[0][2] += av0 * wv.z; acc[0][3] += av0 * wv.w;
            acc[1][0] += av1 * wv.x; acc[1][1] += av1 * wv.y;
            acc[1][2] += av1 * wv.z; acc[1][3] += av1 * wv.w;
            acc[2][0] += av2 * wv.x; acc[2][1] += av2 * wv.y;
            acc[2][2] += av2 * wv.z; acc[2][3] += av2 * wv.w;
            acc[3][0] += av3 * wv.x; acc[3][1] += av3 * wv.y;
            acc[3][2] += av3 * wv.z; acc[3][3] += av3 * wv.w;
        }
    }

    float4 bias = make_float4(0.f, 0.f, 0.f, 0.f);
    if (!isY) bias = *(const float4*)&b[jj];
    float* dstp = isY ? Y : C;
    #pragma unroll
    for (int m = 0; m < 4; ++m) {
        int gn = node0 + n0 + m;
        if (gn < N) {
            float4 r;
            r.x = acc[m][0] + bias.x;
            r.y = acc[m][1] + bias.y;
            r.z = acc[m][2] + bias.z;
            r.w = acc[m][3] + bias.w;
            *(float4*)&dstp[(size_t)gn * F + jj] = r;
        }
    }
}

// ---------------- CSR gather (layer 1):  C[i] += mean Y[in(i)] ------------
template <int F>
__global__ void gather_kernel(const int* __restrict__ row_start,
                              const int* __restrict__ row_end,
                              const int* __restrict__ csr_src,
                              const float* __restrict__ Y,
                              float* __restrict__ C, int N)
{
    constexpr int TPN = F / 4;
    int gid  = blockIdx.x * blockDim.x + threadIdx.x;
    int node = gid / TPN;
    int q    = gid % TPN;
    if (node >= N) return;

    int start = row_start[node];
    int end   = row_end[node];
    float w   = 1.0f / fmaxf((float)(end - start), 1.0f);

    float4 acc = make_float4(0.f, 0.f, 0.f, 0.f);
    for (int j = start; j < end; ++j) {
        int s = csr_src[j];
        float4 v = *(const float4*)&Y[(size_t)s * F + q * 4];
        acc.x += v.x; acc.y += v.y; acc.z += v.z; acc.w += v.w;
    }

    float* o = &C[(size_t)node * F + q * 4];
    float4 c = *(const float4*)o;
    c.x += acc.x * w; c.y += acc.y * w;
    c.z += acc.z * w; c.w += acc.w * w;
    *(float4*)o = c;
}

// ---------------- fused gather2 + final:  out = relu(c2 + mean)@Wfc + bfc -
__global__ void gather_final(const int* __restrict__ row_start,
                             const int* __restrict__ row_end,
                             const int* __restrict__ csr_src,
                             const float* __restrict__ Y,   // y2 [N][16]
                             const float* __restrict__ c2,  // [N][16]
                             const float* __restrict__ Wfc, // [16][2]
                             const float* __restrict__ bfc, // [2]
                             float* __restrict__ out, int N)
{
    int gid  = blockIdx.x * blockDim.x + threadIdx.x;
    int node = gid / 4;
    int q    = gid % 4;
    if (node >= N) return;

    int start = row_start[node];
    int end   = row_end[node];
    float w   = 1.0f / fmaxf((float)(end - start), 1.0f);

    float4 acc = make_float4(0.f, 0.f, 0.f, 0.f);
    for (int j = start; j < end; ++j) {
        int s = csr_src[j];
        float4 v = *(const float4*)&Y[(size_t)s * 16 + q * 4];
        acc.x += v.x; acc.y += v.y; acc.z += v.z; acc.w += v.w;
    }

    float4 c = *(const float4*)&c2[(size_t)node * 16 + q * 4];
    float h0 = fmaxf(c.x + acc.x * w, 0.f);
    float h1 = fmaxf(c.y + acc.y * w, 0.f);
    float h2 = fmaxf(c.z + acc.z * w, 0.f);
    float h3 = fmaxf(c.w + acc.w * w, 0.f);

    const float* Wq = &Wfc[q * 8];
    float o0 = h0 * Wq[0] + h1 * Wq[2] + h2 * Wq[4] + h3 * Wq[6];
    float o1 = h0 * Wq[1] + h1 * Wq[3] + h2 * Wq[5] + h3 * Wq[7];

    o0 += __shfl_xor(o0, 1); o0 += __shfl_xor(o0, 2);
    o1 += __shfl_xor(o1, 1); o1 += __shfl_xor(o1, 2);

    if (q == 0) ((float2*)out)[node] = make_float2(o0 + bfc[0], o1 + bfc[1]);
}

extern "C" void kernel_launch(void* const* d_in, const int* in_sizes, int n_in,
                              void* d_out, int out_size, void* d_ws, size_t ws_size,
                              hipStream_t stream)
{
    const float* x   = (const float*)d_in[0];
    const int*   ei  = (const int*)d_in[1];   // int32 (JAX default)
    const float* W1l = (const float*)d_in[2];
    const float* b1  = (const float*)d_in[3];
    const float* W1r = (const float*)d_in[4];
    const float* W2l = (const float*)d_in[5];
    const float* b2  = (const float*)d_in[6];
    const float* W2r = (const float*)d_in[7];
    const float* Wfc = (const float*)d_in[8];
    const float* bfc = (const float*)d_in[9];
    float* out = (float*)d_out;

    const int N = in_sizes[0] / 128;
    const int E = in_sizes[1] / 2;
    const int* src = ei;
    const int* dst = ei + E;

    const int NBK = (N + BK_SIZE - 1) / BK_SIZE;   // 782

    int*   bucket_cnt  = (int*)d_ws;                // NBK
    int*   bucket_base = bucket_cnt + NBK_MAX;      // NBK
    int*   gcursor     = bucket_base + NBK_MAX;     // NBK
    int*   row_start   = gcursor + NBK_MAX;         // N
    int*   row_end     = row_start + N;             // N
    int*   csr_src     = row_end + N;               // E
    float* y1          = (float*)(csr_src + E);     // N*32
    float* c1          = y1 + (size_t)N * 32;       // N*32
    float* y2          = y1;                        // N*16 (overlays dead y1)
    float* c2          = y1 + (size_t)N * 16;       // N*16
    int*   pk          = (int*)y1;                  // E (dead before gemm1 writes y1)

    // ---- build CSR (bucketed) ----
    hipMemsetAsync(bucket_cnt, 0, (size_t)NBK * sizeof(int), stream);
    hist_buckets<<<196, 256, 0, stream>>>(dst, bucket_cnt, E, NBK);
    scan_buckets<<<1, 1024, 0, stream>>>(bucket_cnt, bucket_base, gcursor, NBK);
    {
        int nb = (E + 256 * EPT - 1) / (256 * EPT);
        bin_scatter<<<nb, 256, 0, stream>>>(src, dst, gcursor, pk, E, NBK);
    }
    bucket_csr<<<NBK, 256, 0, stream>>>(pk, bucket_base, bucket_cnt,
                                        csr_src, row_start, row_end, N);

    // ---- layer 1: y1 = x@W1l, c1 = x@W1r + b1; c1 += mean(y1[in(i)]) ----
    gemm_dual<128, 32, false><<<(N + 63) / 64, TPB, 0, stream>>>(
        x, W1l, W1r, b1, y1, c1, N);
    gather_kernel<32><<<(N * 8 + TPB - 1) / TPB, TPB, 0, stream>>>(
        row_start, row_end, csr_src, y1, c1, N);

    // ---- layer 2: y2 = relu(c1)@W2l, c2 = relu(c1)@W2r + b2 ----
    gemm_dual<32, 16, true><<<(N + 127) / 128, TPB, 0, stream>>>(
        c1, W2l, W2r, b2, y2, c2, N);

    // ---- fused gather2 + final ----
    gather_final<<<(N * 4 + TPB - 1) / TPB, TPB, 0, stream>>>(
        row_start, row_end, csr_src, y2, c2, Wfc, bfc, out, N);
}